// Round 6
// baseline (859.276 us; speedup 1.0000x reference)
//
#include <hip/hip_runtime.h>
#include <hip/hip_bf16.h>

#define NN 20000
#define NE 320000
#define XSTB 256    // xcatb row stride (bf16 elems)
#define CAP 96      // per-node bucket capacity (Poisson(16): P(>=96)~1e-47)
#define GRID 768    // 3 blocks/CU; __launch_bounds__(256,4) guarantees residency
#define NPANEL 1250

typedef __attribute__((ext_vector_type(8))) short short8v;
typedef __attribute__((ext_vector_type(4))) float float4v;

struct bh4 { __hip_bfloat16 a, b, c, d; };

// Wt layout per layer: [128][K] bf16. rows 0..63:(Wtop-Wbot)^T -> Pa; 64..127: Wbot^T -> Pb
#define WT_OFF0 0
#define WT_OFF1 (128 * 64)
#define WT_OFF2 (128 * 64 + 128 * 128)
#define WT_TOT  (128 * 64 + 128 * 128 + 128 * 192)

// device-scope grid barrier: monotone counter per phase slot (memset to 0 each call)
__device__ __forceinline__ void gridbar(int* bar) {
    __threadfence();                       // release: flush this thread's writes
    __syncthreads();                       // (implies vmcnt drain for the block)
    if (threadIdx.x == 0) {
        atomicAdd(bar, 1);                 // device-scope RMW
        while (__hip_atomic_load(bar, __ATOMIC_RELAXED, __HIP_MEMORY_SCOPE_AGENT) < GRID)
            __builtin_amdgcn_s_sleep(2);
    }
    __syncthreads();
    __threadfence();                       // acquire: invalidate stale lines
}

__device__ __forceinline__ float bucket_max(const int* __restrict__ el, int c, int lane,
                                            const __hip_bfloat16* __restrict__ Pbb) {
    float mx = -INFINITY;
    int i = 0;
    for (; i + 4 <= c; i += 4) {
        int s0 = el[i], s1 = el[i + 1], s2 = el[i + 2], s3 = el[i + 3];
        float v0 = __bfloat162float(Pbb[(size_t)s0 * 64 + lane]);
        float v1 = __bfloat162float(Pbb[(size_t)s1 * 64 + lane]);
        float v2 = __bfloat162float(Pbb[(size_t)s2 * 64 + lane]);
        float v3 = __bfloat162float(Pbb[(size_t)s3 * 64 + lane]);
        mx = fmaxf(mx, fmaxf(fmaxf(v0, v1), fmaxf(v2, v3)));
    }
    for (; i < c; ++i)
        mx = fmaxf(mx, __bfloat162float(Pbb[(size_t)el[i] * 64 + lane]));
    return mx;
}

// fused: agg(layer i) for 16 nodes -> LDS + xcatb, then gemm(layer i+1), K=C.
template <int C>
__device__ __forceinline__ void fused_phase(int w, int lane,
                                            const float* __restrict__ PaIn,
                                            const __hip_bfloat16* __restrict__ PbbIn,
                                            const float* __restrict__ b,
                                            const int* __restrict__ cnt,
                                            const int* __restrict__ elist,
                                            __hip_bfloat16* __restrict__ xcatb,
                                            const __hip_bfloat16* __restrict__ Wt,
                                            float* __restrict__ PaOut,
                                            __hip_bfloat16* __restrict__ PbbOut,
                                            __hip_bfloat16 (*newt)[72]) {
    for (int panel = blockIdx.x; panel < NPANEL; panel += GRID) {
        int r0 = panel * 16;
        // phase A: aggregate 4 nodes per wave
#pragma unroll
        for (int nl = 0; nl < 4; ++nl) {
            int local = w * 4 + nl;
            int node = r0 + local;
            int c = cnt[node];
            if (c > CAP) c = CAP;
            float mx = bucket_max(elist + (size_t)node * CAP, c, lane, PbbIn);
            float v = fmaxf(PaIn[(size_t)node * 64 + lane] + b[lane] + mx, 0.f);
            __hip_bfloat16 h = __float2bfloat16(v);
            newt[local][lane] = h;
            xcatb[(size_t)node * XSTB + (C - 64) + lane] = h;
        }
        __syncthreads();
        // phase B: MFMA gemm for this panel (waves 0,1 = halves)
        if (w < 2) {
            int half = w, m = lane & 15, g = lane >> 4;
            const __hip_bfloat16* aptr = xcatb + (size_t)(r0 + m) * XSTB + g * 8;
            const __hip_bfloat16* bptr = Wt + (size_t)(half * 64 + m) * C + g * 8;
            float4v acc[4] = {{0.f,0.f,0.f,0.f},{0.f,0.f,0.f,0.f},
                              {0.f,0.f,0.f,0.f},{0.f,0.f,0.f,0.f}};
#pragma unroll
            for (int k0 = 0; k0 < C; k0 += 32) {
                short8v a;
                if (k0 < C - 64) a = *(const short8v*)(aptr + k0);
                else             a = *(const short8v*)(&newt[m][k0 - (C - 64) + g * 8]);
#pragma unroll
                for (int t = 0; t < 4; ++t) {
                    short8v bb = *(const short8v*)(bptr + (size_t)t * 16 * C + k0);
                    acc[t] = __builtin_amdgcn_mfma_f32_16x16x32_bf16(a, bb, acc[t], 0, 0, 0);
                }
            }
            if (half == 0) {
#pragma unroll
                for (int t = 0; t < 4; ++t)
#pragma unroll
                    for (int r = 0; r < 4; ++r)
                        PaOut[(size_t)(r0 + g * 4 + r) * 64 + t * 16 + m] = acc[t][r];
            } else {
#pragma unroll
                for (int t = 0; t < 4; ++t)
#pragma unroll
                    for (int r = 0; r < 4; ++r)
                        PbbOut[(size_t)(r0 + g * 4 + r) * 64 + t * 16 + m] =
                            __float2bfloat16(acc[t][r]);
            }
        }
        __syncthreads();   // protect newt reuse on next grid-stride iteration
    }
}

__global__ __launch_bounds__(256, 4) void mega_kernel(
    const float* __restrict__ x, const float* __restrict__ W0,
    const float* __restrict__ W1, const float* __restrict__ W2,
    const float* __restrict__ b0, const float* __restrict__ b1,
    const float* __restrict__ b2, const int* __restrict__ esrc,
    const int* __restrict__ edst, __hip_bfloat16* __restrict__ xcatb,
    float* __restrict__ PaA, __hip_bfloat16* __restrict__ PbbA,
    float* __restrict__ PaB, __hip_bfloat16* __restrict__ PbbB,
    __hip_bfloat16* __restrict__ Wt, int* __restrict__ cursor,
    int* __restrict__ elist, int* __restrict__ bar, float* __restrict__ out) {
    int tid = threadIdx.x;
    int w = tid >> 6, lane = tid & 63;
    __shared__ __hip_bfloat16 newt[16][72];
    __shared__ float sm[4][64];

    // ---- P0: x->bf16, Wt build, cursor zero ----
    for (int blk = blockIdx.x; blk < 1521; blk += GRID) {
        if (blk < 1250) {
            int i = blk * 256 + tid;
            int n = i >> 4, c4 = (i & 15) << 2;
            float4 v = *(const float4*)(x + (size_t)n * 64 + c4);
            bh4 o = {__float2bfloat16(v.x), __float2bfloat16(v.y),
                     __float2bfloat16(v.z), __float2bfloat16(v.w)};
            *(bh4*)(xcatb + (size_t)n * XSTB + c4) = o;
        } else if (blk < 1442) {
            int e = (blk - 1250) * 256 + tid;
            const float* W;
            int K, off;
            if (e < WT_OFF1) { W = W0; K = 64;  off = WT_OFF0; }
            else if (e < WT_OFF2) { W = W1; K = 128; off = WT_OFF1; }
            else { W = W2; K = 192; off = WT_OFF2; }
            int el = e - off;
            int j = el / K, k = el - j * K;
            float wv;
            if (j < 64) wv = W[(size_t)k * 64 + j] - W[(size_t)(K + k) * 64 + j];
            else        wv = W[(size_t)(K + k) * 64 + (j - 64)];
            Wt[(size_t)off + (size_t)j * K + k] = __float2bfloat16(wv);
        } else {
            int idx = (blk - 1442) * 256 + tid;
            if (idx < NN) cursor[idx] = 0;
        }
    }
    gridbar(bar + 0);

    // ---- P1: bucket CSR fill || layer-0 GEMM ----
    for (int u = blockIdx.x; u < 1250 + 625; u += GRID) {
        if (u < 1250) {
            int i = u * 256 + tid;
            if (i < NE) {
                int d = edst[i];
                int pos = atomicAdd(cursor + d, 1);
                if (pos < CAP) elist[(size_t)d * CAP + pos] = esrc[i];
            }
        } else {
            int wid = (u - 1250) * 4 + w;      // 0..2499
            int panel = wid >> 1, half = wid & 1;
            int m = lane & 15, g = lane >> 4;
            const __hip_bfloat16* aptr = xcatb + (size_t)(panel * 16 + m) * XSTB + g * 8;
            const __hip_bfloat16* bptr = Wt + (size_t)(half * 64 + m) * 64 + g * 8;
            float4v acc[4] = {{0.f,0.f,0.f,0.f},{0.f,0.f,0.f,0.f},
                              {0.f,0.f,0.f,0.f},{0.f,0.f,0.f,0.f}};
#pragma unroll
            for (int k0 = 0; k0 < 64; k0 += 32) {
                short8v a = *(const short8v*)(aptr + k0);
#pragma unroll
                for (int t = 0; t < 4; ++t) {
                    short8v bb = *(const short8v*)(bptr + (size_t)t * 16 * 64 + k0);
                    acc[t] = __builtin_amdgcn_mfma_f32_16x16x32_bf16(a, bb, acc[t], 0, 0, 0);
                }
            }
            int r0 = panel * 16;
            if (half == 0) {
#pragma unroll
                for (int t = 0; t < 4; ++t)
#pragma unroll
                    for (int r = 0; r < 4; ++r)
                        PaA[(size_t)(r0 + g * 4 + r) * 64 + t * 16 + m] = acc[t][r];
            } else {
#pragma unroll
                for (int t = 0; t < 4; ++t)
#pragma unroll
                    for (int r = 0; r < 4; ++r)
                        PbbA[(size_t)(r0 + g * 4 + r) * 64 + t * 16 + m] =
                            __float2bfloat16(acc[t][r]);
            }
        }
    }
    gridbar(bar + 1);

    // ---- P2: agg0 + gemm1 (K=128) -> PaB/PbbB ----
    fused_phase<128>(w, lane, PaA, PbbA, b0, cursor, elist, xcatb, Wt + WT_OFF1,
                     PaB, PbbB, newt);
    gridbar(bar + 2);

    // ---- P3: agg1 + gemm2 (K=192) -> PaA/PbbA ----
    fused_phase<192>(w, lane, PaB, PbbB, b1, cursor, elist, xcatb, Wt + WT_OFF2,
                     PaA, PbbA, newt);
    gridbar(bar + 3);

    // ---- P4: agg2 + final max ----
    for (int u = blockIdx.x; u < 5000; u += GRID) {
        int node = u * 4 + w;
        int c = cursor[node];
        if (c > CAP) c = CAP;
        float mx = bucket_max(elist + (size_t)node * CAP, c, lane, PbbA);
        float v = fmaxf(PaA[(size_t)node * 64 + lane] + b2[lane] + mx, 0.f);
        sm[w][lane] = v;                      // intra-wave only: no barrier needed
        float m;
        if (lane < 48) {
            bh4 q = *(const bh4*)(xcatb + (size_t)node * XSTB + (lane << 2));
            float f0 = __bfloat162float(q.a), f1 = __bfloat162float(q.b);
            float f2 = __bfloat162float(q.c), f3 = __bfloat162float(q.d);
            m = fmaxf(fmaxf(f0, f1), fmaxf(f2, f3));
        } else {
            const float* p = &sm[w][(lane - 48) << 2];
            m = fmaxf(fmaxf(p[0], p[1]), fmaxf(p[2], p[3]));
        }
        out[(size_t)node * 64 + lane] = m;
    }
}

extern "C" void kernel_launch(void* const* d_in, const int* in_sizes, int n_in,
                              void* d_out, int out_size, void* d_ws, size_t ws_size,
                              hipStream_t stream) {
    const float* x = (const float*)d_in[0];
    const float* W0 = (const float*)d_in[1];
    const float* W1 = (const float*)d_in[3];
    const float* W2 = (const float*)d_in[5];
    const float* b0 = (const float*)d_in[2];
    const float* b1 = (const float*)d_in[4];
    const float* b2 = (const float*)d_in[6];
    const int* eidx = (const int*)d_in[7];
    const int* esrc = eidx;
    const int* edst = eidx + NE;
    float* out = (float*)d_out;

    char* w = (char*)d_ws;
    int* bar = (int*)w;                          w += 256;
    __hip_bfloat16* xcatb = (__hip_bfloat16*)w;  w += (size_t)NN * XSTB * 2;
    float* PaA = (float*)w;                      w += (size_t)NN * 64 * 4;
    __hip_bfloat16* PbbA = (__hip_bfloat16*)w;   w += (size_t)NN * 64 * 2;
    float* PaB = (float*)w;                      w += (size_t)NN * 64 * 4;
    __hip_bfloat16* PbbB = (__hip_bfloat16*)w;   w += (size_t)NN * 64 * 2;
    __hip_bfloat16* Wt = (__hip_bfloat16*)w;     w += (size_t)WT_TOT * 2;
    int* cursor = (int*)w;                       w += (size_t)NN * 4;
    int* elist = (int*)w;

    hipMemsetAsync(bar, 0, 4 * sizeof(int), stream);
    mega_kernel<<<GRID, 256, 0, stream>>>(x, W0, W1, W2, b0, b1, b2, esrc, edst,
                                          xcatb, PaA, PbbA, PaB, PbbB, Wt, cursor,
                                          elist, bar, out);
}

// Round 7
// 735.047 us; speedup vs baseline: 1.1690x; 1.1690x over previous
//
#include <hip/hip_runtime.h>
#include <hip/hip_bf16.h>

#define NN 20000
#define NE 320000
#define XSTB 256    // xcatb row stride (bf16 elems)
#define CAP 96      // per-node bucket capacity (Poisson(16): P(>=96)~1e-47)
#define GRID 625    // exact balance: P1 3 chunks, P2/P3 2 panels, P4 8 nodes-groups per block
#define NPANEL 1250

typedef __attribute__((ext_vector_type(8))) short short8v;
typedef __attribute__((ext_vector_type(4))) float float4v;

struct bh4 { __hip_bfloat16 a, b, c, d; };

// Wt layout per layer: [128][K] bf16. rows 0..63:(Wtop-Wbot)^T -> Pa; 64..127: Wbot^T -> Pb
#define WT_OFF0 0
#define WT_OFF1 (128 * 64)
#define WT_OFF2 (128 * 64 + 128 * 128)
#define WT_TOT  (128 * 64 + 128 * 128 + 128 * 192)

// Device-scope grid barrier. Round-6 lesson: AGENT-scope spin loads were served
// stale from the local (non-cross-coherent) XCD L2 -> ~200us/barrier. Poll at
// SYSTEM scope (sc0+sc1, bypasses L1+L2) with a periodic device-RMW fallback
// (RMWs are cross-XCD coherent per m20), s_sleep backoff between polls.
__device__ __forceinline__ void gridbar(int* bar) {
    __threadfence();                       // release
    __syncthreads();
    if (threadIdx.x == 0) {
        atomicAdd(bar, 1);
        int polls = 0;
        while (true) {
            int v;
            if ((++polls & 15) == 0)
                v = atomicAdd(bar, 0);     // coherent RMW read (progress guarantee)
            else
                v = __hip_atomic_load(bar, __ATOMIC_RELAXED, __HIP_MEMORY_SCOPE_SYSTEM);
            if (v >= GRID) break;
            __builtin_amdgcn_s_sleep(8);
        }
    }
    __syncthreads();
    __threadfence();                       // acquire
}

__device__ __forceinline__ float bucket_max(const int* __restrict__ el, int c, int lane,
                                            const __hip_bfloat16* __restrict__ Pbb) {
    float mx = -INFINITY;
    int i = 0;
    for (; i + 4 <= c; i += 4) {
        int s0 = el[i], s1 = el[i + 1], s2 = el[i + 2], s3 = el[i + 3];
        float v0 = __bfloat162float(Pbb[(size_t)s0 * 64 + lane]);
        float v1 = __bfloat162float(Pbb[(size_t)s1 * 64 + lane]);
        float v2 = __bfloat162float(Pbb[(size_t)s2 * 64 + lane]);
        float v3 = __bfloat162float(Pbb[(size_t)s3 * 64 + lane]);
        mx = fmaxf(mx, fmaxf(fmaxf(v0, v1), fmaxf(v2, v3)));
    }
    for (; i < c; ++i)
        mx = fmaxf(mx, __bfloat162float(Pbb[(size_t)el[i] * 64 + lane]));
    return mx;
}

// fused: agg(layer i) for 16 nodes -> LDS + xcatb, then gemm(layer i+1), K=C.
template <int C>
__device__ __forceinline__ void fused_phase(int w, int lane,
                                            const float* __restrict__ PaIn,
                                            const __hip_bfloat16* __restrict__ PbbIn,
                                            const float* __restrict__ b,
                                            const int* __restrict__ cnt,
                                            const int* __restrict__ elist,
                                            __hip_bfloat16* __restrict__ xcatb,
                                            const __hip_bfloat16* __restrict__ Wt,
                                            float* __restrict__ PaOut,
                                            __hip_bfloat16* __restrict__ PbbOut,
                                            __hip_bfloat16 (*newt)[72]) {
    for (int panel = blockIdx.x; panel < NPANEL; panel += GRID) {
        int r0 = panel * 16;
        // phase A: aggregate 4 nodes per wave
#pragma unroll
        for (int nl = 0; nl < 4; ++nl) {
            int local = w * 4 + nl;
            int node = r0 + local;
            int c = cnt[node];
            if (c > CAP) c = CAP;
            float mx = bucket_max(elist + (size_t)node * CAP, c, lane, PbbIn);
            float v = fmaxf(PaIn[(size_t)node * 64 + lane] + b[lane] + mx, 0.f);
            __hip_bfloat16 h = __float2bfloat16(v);
            newt[local][lane] = h;
            xcatb[(size_t)node * XSTB + (C - 64) + lane] = h;
        }
        __syncthreads();
        // phase B: MFMA gemm for this panel (waves 0,1 = halves)
        if (w < 2) {
            int half = w, m = lane & 15, g = lane >> 4;
            const __hip_bfloat16* aptr = xcatb + (size_t)(r0 + m) * XSTB + g * 8;
            const __hip_bfloat16* bptr = Wt + (size_t)(half * 64 + m) * C + g * 8;
            float4v acc[4] = {{0.f,0.f,0.f,0.f},{0.f,0.f,0.f,0.f},
                              {0.f,0.f,0.f,0.f},{0.f,0.f,0.f,0.f}};
#pragma unroll
            for (int k0 = 0; k0 < C; k0 += 32) {
                short8v a;
                if (k0 < C - 64) a = *(const short8v*)(aptr + k0);
                else             a = *(const short8v*)(&newt[m][k0 - (C - 64) + g * 8]);
#pragma unroll
                for (int t = 0; t < 4; ++t) {
                    short8v bb = *(const short8v*)(bptr + (size_t)t * 16 * C + k0);
                    acc[t] = __builtin_amdgcn_mfma_f32_16x16x32_bf16(a, bb, acc[t], 0, 0, 0);
                }
            }
            if (half == 0) {
#pragma unroll
                for (int t = 0; t < 4; ++t)
#pragma unroll
                    for (int r = 0; r < 4; ++r)
                        PaOut[(size_t)(r0 + g * 4 + r) * 64 + t * 16 + m] = acc[t][r];
            } else {
#pragma unroll
                for (int t = 0; t < 4; ++t)
#pragma unroll
                    for (int r = 0; r < 4; ++r)
                        PbbOut[(size_t)(r0 + g * 4 + r) * 64 + t * 16 + m] =
                            __float2bfloat16(acc[t][r]);
            }
        }
        __syncthreads();   // protect newt reuse on next grid-stride iteration
    }
}

__global__ __launch_bounds__(256, 4) void mega_kernel(
    const float* __restrict__ x, const float* __restrict__ W0,
    const float* __restrict__ W1, const float* __restrict__ W2,
    const float* __restrict__ b0, const float* __restrict__ b1,
    const float* __restrict__ b2, const int* __restrict__ esrc,
    const int* __restrict__ edst, __hip_bfloat16* __restrict__ xcatb,
    float* __restrict__ PaA, __hip_bfloat16* __restrict__ PbbA,
    float* __restrict__ PaB, __hip_bfloat16* __restrict__ PbbB,
    __hip_bfloat16* __restrict__ Wt, int* __restrict__ cursor,
    int* __restrict__ elist, int* __restrict__ bar, float* __restrict__ out) {
    int tid = threadIdx.x;
    int w = tid >> 6, lane = tid & 63;
    __shared__ __hip_bfloat16 newt[16][72];
    __shared__ float sm[4][64];

    // ---- P0: x->bf16, Wt build, cursor zero ----
    for (int blk = blockIdx.x; blk < 1521; blk += GRID) {
        if (blk < 1250) {
            int i = blk * 256 + tid;
            int n = i >> 4, c4 = (i & 15) << 2;
            float4 v = *(const float4*)(x + (size_t)n * 64 + c4);
            bh4 o = {__float2bfloat16(v.x), __float2bfloat16(v.y),
                     __float2bfloat16(v.z), __float2bfloat16(v.w)};
            *(bh4*)(xcatb + (size_t)n * XSTB + c4) = o;
        } else if (blk < 1442) {
            int e = (blk - 1250) * 256 + tid;
            const float* W;
            int K, off;
            if (e < WT_OFF1) { W = W0; K = 64;  off = WT_OFF0; }
            else if (e < WT_OFF2) { W = W1; K = 128; off = WT_OFF1; }
            else { W = W2; K = 192; off = WT_OFF2; }
            int el = e - off;
            int j = el / K, k = el - j * K;
            float wv;
            if (j < 64) wv = W[(size_t)k * 64 + j] - W[(size_t)(K + k) * 64 + j];
            else        wv = W[(size_t)(K + k) * 64 + (j - 64)];
            Wt[(size_t)off + (size_t)j * K + k] = __float2bfloat16(wv);
        } else {
            int idx = (blk - 1442) * 256 + tid;
            if (idx < NN) cursor[idx] = 0;
        }
    }
    gridbar(bar + 0);

    // ---- P1: bucket CSR fill || layer-0 GEMM ----
    for (int u = blockIdx.x; u < 1250 + 625; u += GRID) {
        if (u < 1250) {
            int i = u * 256 + tid;
            if (i < NE) {
                int d = edst[i];
                int pos = atomicAdd(cursor + d, 1);
                if (pos < CAP) elist[(size_t)d * CAP + pos] = esrc[i];
            }
        } else {
            int wid = (u - 1250) * 4 + w;      // 0..2499
            int panel = wid >> 1, half = wid & 1;
            int m = lane & 15, g = lane >> 4;
            const __hip_bfloat16* aptr = xcatb + (size_t)(panel * 16 + m) * XSTB + g * 8;
            const __hip_bfloat16* bptr = Wt + (size_t)(half * 64 + m) * 64 + g * 8;
            float4v acc[4] = {{0.f,0.f,0.f,0.f},{0.f,0.f,0.f,0.f},
                              {0.f,0.f,0.f,0.f},{0.f,0.f,0.f,0.f}};
#pragma unroll
            for (int k0 = 0; k0 < 64; k0 += 32) {
                short8v a = *(const short8v*)(aptr + k0);
#pragma unroll
                for (int t = 0; t < 4; ++t) {
                    short8v bb = *(const short8v*)(bptr + (size_t)t * 16 * 64 + k0);
                    acc[t] = __builtin_amdgcn_mfma_f32_16x16x32_bf16(a, bb, acc[t], 0, 0, 0);
                }
            }
            int r0 = panel * 16;
            if (half == 0) {
#pragma unroll
                for (int t = 0; t < 4; ++t)
#pragma unroll
                    for (int r = 0; r < 4; ++r)
                        PaA[(size_t)(r0 + g * 4 + r) * 64 + t * 16 + m] = acc[t][r];
            } else {
#pragma unroll
                for (int t = 0; t < 4; ++t)
#pragma unroll
                    for (int r = 0; r < 4; ++r)
                        PbbA[(size_t)(r0 + g * 4 + r) * 64 + t * 16 + m] =
                            __float2bfloat16(acc[t][r]);
            }
        }
    }
    gridbar(bar + 1);

    // ---- P2: agg0 + gemm1 (K=128) -> PaB/PbbB ----
    fused_phase<128>(w, lane, PaA, PbbA, b0, cursor, elist, xcatb, Wt + WT_OFF1,
                     PaB, PbbB, newt);
    gridbar(bar + 2);

    // ---- P3: agg1 + gemm2 (K=192) -> PaA/PbbA ----
    fused_phase<192>(w, lane, PaB, PbbB, b1, cursor, elist, xcatb, Wt + WT_OFF2,
                     PaA, PbbA, newt);
    gridbar(bar + 3);

    // ---- P4: agg2 + final max ----
    for (int u = blockIdx.x; u < 5000; u += GRID) {
        int node = u * 4 + w;
        int c = cursor[node];
        if (c > CAP) c = CAP;
        float mx = bucket_max(elist + (size_t)node * CAP, c, lane, PbbA);
        float v = fmaxf(PaA[(size_t)node * 64 + lane] + b2[lane] + mx, 0.f);
        sm[w][lane] = v;                      // intra-wave only: no barrier needed
        float m;
        if (lane < 48) {
            bh4 q = *(const bh4*)(xcatb + (size_t)node * XSTB + (lane << 2));
            float f0 = __bfloat162float(q.a), f1 = __bfloat162float(q.b);
            float f2 = __bfloat162float(q.c), f3 = __bfloat162float(q.d);
            m = fmaxf(fmaxf(f0, f1), fmaxf(f2, f3));
        } else {
            const float* p = &sm[w][(lane - 48) << 2];
            m = fmaxf(fmaxf(p[0], p[1]), fmaxf(p[2], p[3]));
        }
        out[(size_t)node * 64 + lane] = m;
    }
}

extern "C" void kernel_launch(void* const* d_in, const int* in_sizes, int n_in,
                              void* d_out, int out_size, void* d_ws, size_t ws_size,
                              hipStream_t stream) {
    const float* x = (const float*)d_in[0];
    const float* W0 = (const float*)d_in[1];
    const float* W1 = (const float*)d_in[3];
    const float* W2 = (const float*)d_in[5];
    const float* b0 = (const float*)d_in[2];
    const float* b1 = (const float*)d_in[4];
    const float* b2 = (const float*)d_in[6];
    const int* eidx = (const int*)d_in[7];
    const int* esrc = eidx;
    const int* edst = eidx + NE;
    float* out = (float*)d_out;

    char* w = (char*)d_ws;
    int* bar = (int*)w;                          w += 256;
    __hip_bfloat16* xcatb = (__hip_bfloat16*)w;  w += (size_t)NN * XSTB * 2;
    float* PaA = (float*)w;                      w += (size_t)NN * 64 * 4;
    __hip_bfloat16* PbbA = (__hip_bfloat16*)w;   w += (size_t)NN * 64 * 2;
    float* PaB = (float*)w;                      w += (size_t)NN * 64 * 4;
    __hip_bfloat16* PbbB = (__hip_bfloat16*)w;   w += (size_t)NN * 64 * 2;
    __hip_bfloat16* Wt = (__hip_bfloat16*)w;     w += (size_t)WT_TOT * 2;
    int* cursor = (int*)w;                       w += (size_t)NN * 4;
    int* elist = (int*)w;

    hipMemsetAsync(bar, 0, 4 * sizeof(int), stream);
    mega_kernel<<<GRID, 256, 0, stream>>>(x, W0, W1, W2, b0, b1, b2, esrc, edst,
                                          xcatb, PaA, PbbA, PaB, PbbB, Wt, cursor,
                                          elist, bar, out);
}

// Round 8
// 127.159 us; speedup vs baseline: 6.7575x; 5.7805x over previous
//
#include <hip/hip_runtime.h>
#include <hip/hip_bf16.h>

#define NN 20000
#define NE 320000
#define XSTB 256    // xcatb row stride (bf16 elems)
#define CAP 96      // per-node bucket capacity (Poisson(16): P(>=96)~1e-47)

typedef __attribute__((ext_vector_type(8))) short short8v;
typedef __attribute__((ext_vector_type(4))) float float4v;

struct bh4 { __hip_bfloat16 a, b, c, d; };

// Global Wt layout (layers 1,2 only; layer 0 is built in-LDS by gemm0 blocks):
// per layer [128][K] bf16: rows 0..63 = (Wtop-Wbot)^T -> Pa; rows 64..127 = Wbot^T -> Pb
#define WT_OFF1 0
#define WT_OFF2 (128 * 128)
#define WT_TOT  (128 * 128 + 128 * 192)   // 40960 elems

__device__ __forceinline__ float bucket_max(const int* __restrict__ el, int c, int lane,
                                            const __hip_bfloat16* __restrict__ Pbb) {
    float mx = -INFINITY;
    int i = 0;
    for (; i + 4 <= c; i += 4) {
        int s0 = el[i], s1 = el[i + 1], s2 = el[i + 2], s3 = el[i + 3];
        float v0 = __bfloat162float(Pbb[(size_t)s0 * 64 + lane]);
        float v1 = __bfloat162float(Pbb[(size_t)s1 * 64 + lane]);
        float v2 = __bfloat162float(Pbb[(size_t)s2 * 64 + lane]);
        float v3 = __bfloat162float(Pbb[(size_t)s3 * 64 + lane]);
        mx = fmaxf(mx, fmaxf(fmaxf(v0, v1), fmaxf(v2, v3)));
    }
    for (; i < c; ++i)
        mx = fmaxf(mx, __bfloat162float(Pbb[(size_t)el[i] * 64 + lane]));
    return mx;
}

// ---- K1: gemm0 || fillb || x->bf16 || Wt(1,2) build -- all independent jobs ----
// blocks [0,625): gemm0 (A from fp32 x, B from LDS-built Wt0)
// blocks [625,1875): bucket CSR fill (cursor pre-zeroed by memset)
// blocks [1875,3125): x -> xcatb bf16
// blocks [3125,3285): global Wt build, layers 1,2
__global__ __launch_bounds__(256, 4) void k1_kernel(
    const float* __restrict__ x, const float* __restrict__ W0,
    const float* __restrict__ W1, const float* __restrict__ W2,
    const int* __restrict__ esrc, const int* __restrict__ edst,
    __hip_bfloat16* __restrict__ xcatb, __hip_bfloat16* __restrict__ Wt,
    int* __restrict__ cursor, int* __restrict__ elist,
    float* __restrict__ Pa, __hip_bfloat16* __restrict__ Pbb) {
    __shared__ __hip_bfloat16 Ws0[128][72];
    int blk = blockIdx.x, tid = threadIdx.x;
    int w = tid >> 6, lane = tid & 63;

    if (blk < 625) {
        // build transformed W0 into LDS (coalesced over W0 rows)
        for (int e = tid; e < 4096; e += 256) {
            int r = e >> 6, j = e & 63;            // r = k index, j = out col
            float wt = W0[r * 64 + j];
            float wb = W0[(64 + r) * 64 + j];
            Ws0[j][r] = __float2bfloat16(wt - wb);
            Ws0[64 + j][r] = __float2bfloat16(wb);
        }
        __syncthreads();
        int wid = blk * 4 + w;                     // 0..2499
        int panel = wid >> 1, half = wid & 1;
        int m = lane & 15, g = lane >> 4;
        const float* aptr = x + (size_t)(panel * 16 + m) * 64 + g * 8;
        float4v acc[4] = {{0.f,0.f,0.f,0.f},{0.f,0.f,0.f,0.f},
                          {0.f,0.f,0.f,0.f},{0.f,0.f,0.f,0.f}};
#pragma unroll
        for (int k0 = 0; k0 < 64; k0 += 32) {
            float4 a0 = *(const float4*)(aptr + k0);
            float4 a1 = *(const float4*)(aptr + k0 + 4);
            __hip_bfloat16 ah[8] = {
                __float2bfloat16(a0.x), __float2bfloat16(a0.y),
                __float2bfloat16(a0.z), __float2bfloat16(a0.w),
                __float2bfloat16(a1.x), __float2bfloat16(a1.y),
                __float2bfloat16(a1.z), __float2bfloat16(a1.w)};
            short8v a = *(const short8v*)ah;
#pragma unroll
            for (int t = 0; t < 4; ++t) {
                short8v bb = *(const short8v*)(&Ws0[half * 64 + t * 16 + m][k0 + g * 8]);
                acc[t] = __builtin_amdgcn_mfma_f32_16x16x32_bf16(a, bb, acc[t], 0, 0, 0);
            }
        }
        int r0 = panel * 16;
        if (half == 0) {
#pragma unroll
            for (int t = 0; t < 4; ++t)
#pragma unroll
                for (int r = 0; r < 4; ++r)
                    Pa[(size_t)(r0 + g * 4 + r) * 64 + t * 16 + m] = acc[t][r];
        } else {
#pragma unroll
            for (int t = 0; t < 4; ++t)
#pragma unroll
                for (int r = 0; r < 4; ++r)
                    Pbb[(size_t)(r0 + g * 4 + r) * 64 + t * 16 + m] =
                        __float2bfloat16(acc[t][r]);
        }
    } else if (blk < 1875) {
        int i = (blk - 625) * 256 + tid;           // < NE exactly
        int d = edst[i];
        int pos = atomicAdd(cursor + d, 1);
        if (pos < CAP) elist[(size_t)d * CAP + pos] = esrc[i];
    } else if (blk < 3125) {
        int i = (blk - 1875) * 256 + tid;          // 320000 quads exactly
        int n = i >> 4, c4 = (i & 15) << 2;
        float4 v = *(const float4*)(x + (size_t)n * 64 + c4);
        bh4 o = {__float2bfloat16(v.x), __float2bfloat16(v.y),
                 __float2bfloat16(v.z), __float2bfloat16(v.w)};
        *(bh4*)(xcatb + (size_t)n * XSTB + c4) = o;
    } else {
        int e = (blk - 3125) * 256 + tid;          // 40960 exactly
        const float* W;
        int K, off;
        if (e < WT_OFF2) { W = W1; K = 128; off = WT_OFF1; }
        else             { W = W2; K = 192; off = WT_OFF2; }
        int el = e - off;
        int j = el / K, k = el - j * K;
        float wv;
        if (j < 64) wv = W[(size_t)k * 64 + j] - W[(size_t)(K + k) * 64 + j];
        else        wv = W[(size_t)(K + k) * 64 + (j - 64)];
        Wt[(size_t)off + (size_t)j * K + k] = __float2bfloat16(wv);
    }
}

// ---- fused: agg(layer i) for 32 nodes -> LDS + xcatb, then gemm(layer i+1) over K=C.
// 625 blocks; phase A: 4 waves x 8 nodes; phase B: 4 waves = 2 panels x 2 halves.
template <int C>
__global__ __launch_bounds__(256, 4) void fused2_kernel(
    const float* __restrict__ PaIn, const __hip_bfloat16* __restrict__ PbbIn,
    const float* __restrict__ b, const int* __restrict__ cnt,
    const int* __restrict__ elist, __hip_bfloat16* __restrict__ xcatb,
    const __hip_bfloat16* __restrict__ Wt, float* __restrict__ PaOut,
    __hip_bfloat16* __restrict__ PbbOut) {
    __shared__ __hip_bfloat16 newt[32][72];
    int tid = threadIdx.x;
    int w = tid >> 6, lane = tid & 63;
    int base = blockIdx.x * 32;

    // phase A: aggregate 8 nodes per wave
#pragma unroll
    for (int nl = 0; nl < 8; ++nl) {
        int local = w * 8 + nl;
        int node = base + local;
        int c = cnt[node];
        if (c > CAP) c = CAP;
        float mx = bucket_max(elist + (size_t)node * CAP, c, lane, PbbIn);
        float v = fmaxf(PaIn[(size_t)node * 64 + lane] + b[lane] + mx, 0.f);
        __hip_bfloat16 h = __float2bfloat16(v);
        newt[local][lane] = h;
        xcatb[(size_t)node * XSTB + (C - 64) + lane] = h;
    }
    __syncthreads();

    // phase B: all 4 waves; wave w -> panel_local = w>>1, half = w&1
    int pl = w >> 1, half = w & 1;
    int panel = blockIdx.x * 2 + pl;
    int r0 = panel * 16;
    int m = lane & 15, g = lane >> 4;
    const __hip_bfloat16* aptr = xcatb + (size_t)(r0 + m) * XSTB + g * 8;
    const __hip_bfloat16* bptr = Wt + (size_t)(half * 64 + m) * C + g * 8;
    float4v acc[4] = {{0.f,0.f,0.f,0.f},{0.f,0.f,0.f,0.f},
                      {0.f,0.f,0.f,0.f},{0.f,0.f,0.f,0.f}};
#pragma unroll
    for (int k0 = 0; k0 < C; k0 += 32) {
        short8v a;
        if (k0 < C - 64) a = *(const short8v*)(aptr + k0);
        else             a = *(const short8v*)(&newt[pl * 16 + m][k0 - (C - 64) + g * 8]);
#pragma unroll
        for (int t = 0; t < 4; ++t) {
            short8v bb = *(const short8v*)(bptr + (size_t)t * 16 * C + k0);
            acc[t] = __builtin_amdgcn_mfma_f32_16x16x32_bf16(a, bb, acc[t], 0, 0, 0);
        }
    }
    if (half == 0) {
#pragma unroll
        for (int t = 0; t < 4; ++t)
#pragma unroll
            for (int r = 0; r < 4; ++r)
                PaOut[(size_t)(r0 + g * 4 + r) * 64 + t * 16 + m] = acc[t][r];
    } else {
#pragma unroll
        for (int t = 0; t < 4; ++t)
#pragma unroll
            for (int r = 0; r < 4; ++r)
                PbbOut[(size_t)(r0 + g * 4 + r) * 64 + t * 16 + m] =
                    __float2bfloat16(acc[t][r]);
    }
}

// ---- last layer agg + final max (32 nodes/block) ----
__global__ __launch_bounds__(256, 4) void aggf_kernel(
    const float* __restrict__ Pa, const __hip_bfloat16* __restrict__ Pbb,
    const float* __restrict__ b, const int* __restrict__ cnt,
    const int* __restrict__ elist, const __hip_bfloat16* __restrict__ xcatb,
    float* __restrict__ out) {
    __shared__ float sm[4][64];
    int w = threadIdx.x >> 6, lane = threadIdx.x & 63;
    int base = blockIdx.x * 32;
#pragma unroll
    for (int nl = 0; nl < 8; ++nl) {
        int node = base + w * 8 + nl;
        int c = cnt[node];
        if (c > CAP) c = CAP;
        float mx = bucket_max(elist + (size_t)node * CAP, c, lane, Pbb);
        float v = fmaxf(Pa[(size_t)node * 64 + lane] + b[lane] + mx, 0.f);
        sm[w][lane] = v;                      // intra-wave produce/consume
        float m;
        if (lane < 48) {
            bh4 q = *(const bh4*)(xcatb + (size_t)node * XSTB + (lane << 2));
            float f0 = __bfloat162float(q.a), f1 = __bfloat162float(q.b);
            float f2 = __bfloat162float(q.c), f3 = __bfloat162float(q.d);
            m = fmaxf(fmaxf(f0, f1), fmaxf(f2, f3));
        } else {
            const float* p = &sm[w][(lane - 48) << 2];
            m = fmaxf(fmaxf(p[0], p[1]), fmaxf(p[2], p[3]));
        }
        out[(size_t)node * 64 + lane] = m;
    }
}

extern "C" void kernel_launch(void* const* d_in, const int* in_sizes, int n_in,
                              void* d_out, int out_size, void* d_ws, size_t ws_size,
                              hipStream_t stream) {
    const float* x = (const float*)d_in[0];
    const float* W0 = (const float*)d_in[1];
    const float* W1 = (const float*)d_in[3];
    const float* W2 = (const float*)d_in[5];
    const float* b0 = (const float*)d_in[2];
    const float* b1 = (const float*)d_in[4];
    const float* b2 = (const float*)d_in[6];
    const int* eidx = (const int*)d_in[7];
    const int* esrc = eidx;
    const int* edst = eidx + NE;
    float* out = (float*)d_out;

    char* w = (char*)d_ws;
    __hip_bfloat16* xcatb = (__hip_bfloat16*)w;  w += (size_t)NN * XSTB * 2;
    float* PaA = (float*)w;                      w += (size_t)NN * 64 * 4;
    __hip_bfloat16* PbbA = (__hip_bfloat16*)w;   w += (size_t)NN * 64 * 2;
    float* PaB = (float*)w;                      w += (size_t)NN * 64 * 4;
    __hip_bfloat16* PbbB = (__hip_bfloat16*)w;   w += (size_t)NN * 64 * 2;
    __hip_bfloat16* Wt = (__hip_bfloat16*)w;     w += (size_t)WT_TOT * 2;
    int* cursor = (int*)w;                       w += (size_t)NN * 4;
    int* elist = (int*)w;

    hipMemsetAsync(cursor, 0, (size_t)NN * 4, stream);
    k1_kernel<<<3285, 256, 0, stream>>>(x, W0, W1, W2, esrc, edst, xcatb, Wt,
                                        cursor, elist, PaA, PbbA);
    fused2_kernel<128><<<625, 256, 0, stream>>>(PaA, PbbA, b0, cursor, elist, xcatb,
                                                Wt + WT_OFF1, PaB, PbbB);
    fused2_kernel<192><<<625, 256, 0, stream>>>(PaB, PbbB, b1, cursor, elist, xcatb,
                                                Wt + WT_OFF2, PaA, PbbA);
    aggf_kernel<<<625, 256, 0, stream>>>(PaA, PbbA, b2, cursor, elist, xcatb, out);
}

// Round 9
// 127.105 us; speedup vs baseline: 6.7604x; 1.0004x over previous
//
#include <hip/hip_runtime.h>
#include <hip/hip_bf16.h>

#define NN 20000
#define NE 320000
#define XSTB 256    // xcatb row stride (bf16 elems)
#define CAP 96      // per-node bucket capacity (Poisson(16): P(>=96)~1e-47)

typedef __attribute__((ext_vector_type(8))) short short8v;
typedef __attribute__((ext_vector_type(4))) float float4v;

struct bh4 { __hip_bfloat16 a, b, c, d; };

// Global Wt layout (layers 1,2; layer 0 built in-LDS by gemm0 blocks):
// per layer [128][K] bf16: rows 0..63 = (Wtop-Wbot)^T -> Pa; rows 64..127 = Wbot^T -> Pb
#define WT_OFF1 0
#define WT_OFF2 (128 * 128)
#define WT_TOT  (128 * 128 + 128 * 192)   // 40960 elems

__device__ __forceinline__ float bucket_max(const int* __restrict__ el, int c, int lane,
                                            const __hip_bfloat16* __restrict__ Pbb) {
    float mx = -INFINITY;
    int i = 0;
    for (; i + 4 <= c; i += 4) {
        int s0 = el[i], s1 = el[i + 1], s2 = el[i + 2], s3 = el[i + 3];
        float v0 = __bfloat162float(Pbb[(size_t)s0 * 64 + lane]);
        float v1 = __bfloat162float(Pbb[(size_t)s1 * 64 + lane]);
        float v2 = __bfloat162float(Pbb[(size_t)s2 * 64 + lane]);
        float v3 = __bfloat162float(Pbb[(size_t)s3 * 64 + lane]);
        mx = fmaxf(mx, fmaxf(fmaxf(v0, v1), fmaxf(v2, v3)));
    }
    for (; i < c; ++i)
        mx = fmaxf(mx, __bfloat162float(Pbb[(size_t)el[i] * 64 + lane]));
    return mx;
}

// ---- K0: zero cursor || x->bf16 || Wt(1,2) build -- all independent ----
// blocks [0,20): cursor zero (int4); [20,1270): x->xcatb; [1270,1430): Wt build.
__global__ __launch_bounds__(256, 4) void k0_kernel(
    const float* __restrict__ x, const float* __restrict__ W1,
    const float* __restrict__ W2, __hip_bfloat16* __restrict__ xcatb,
    __hip_bfloat16* __restrict__ Wt, int* __restrict__ cursor) {
    int blk = blockIdx.x, tid = threadIdx.x;
    if (blk < 20) {
        int q = blk * 256 + tid;                   // 5120 >= 5000 int4
        if (q < NN / 4) *((int4*)cursor + q) = make_int4(0, 0, 0, 0);
    } else if (blk < 1270) {
        int i = (blk - 20) * 256 + tid;            // 320000 quads exactly
        int n = i >> 4, c4 = (i & 15) << 2;
        float4 v = *(const float4*)(x + (size_t)n * 64 + c4);
        bh4 o = {__float2bfloat16(v.x), __float2bfloat16(v.y),
                 __float2bfloat16(v.z), __float2bfloat16(v.w)};
        *(bh4*)(xcatb + (size_t)n * XSTB + c4) = o;
    } else {
        int e = (blk - 1270) * 256 + tid;          // 40960 exactly
        const float* W;
        int K, off;
        if (e < WT_OFF2) { W = W1; K = 128; off = WT_OFF1; }
        else             { W = W2; K = 192; off = WT_OFF2; }
        int el = e - off;
        int j = el / K, k = el - j * K;
        float wv;
        if (j < 64) wv = W[(size_t)k * 64 + j] - W[(size_t)(K + k) * 64 + j];
        else        wv = W[(size_t)(K + k) * 64 + (j - 64)];
        Wt[(size_t)off + (size_t)j * K + k] = __float2bfloat16(wv);
    }
}

// ---- K1: gemm0 || bucket CSR fill ----
// blocks [0,625): gemm0 (A from fp32 x, B from LDS-built W0'); [625,1875): fill.
__global__ __launch_bounds__(256, 4) void k1_kernel(
    const float* __restrict__ x, const float* __restrict__ W0,
    const int* __restrict__ esrc, const int* __restrict__ edst,
    int* __restrict__ cursor, int* __restrict__ elist,
    float* __restrict__ Pa, __hip_bfloat16* __restrict__ Pbb) {
    __shared__ __hip_bfloat16 Ws0[128][72];
    int blk = blockIdx.x, tid = threadIdx.x;
    int w = tid >> 6, lane = tid & 63;

    if (blk < 625) {
        for (int e = tid; e < 4096; e += 256) {
            int r = e >> 6, j = e & 63;            // r = k index, j = out col
            float wt = W0[r * 64 + j];
            float wb = W0[(64 + r) * 64 + j];
            Ws0[j][r] = __float2bfloat16(wt - wb);
            Ws0[64 + j][r] = __float2bfloat16(wb);
        }
        __syncthreads();
        int wid = blk * 4 + w;                     // 0..2499
        int panel = wid >> 1, half = wid & 1;
        int m = lane & 15, g = lane >> 4;
        const float* aptr = x + (size_t)(panel * 16 + m) * 64 + g * 8;
        float4v acc[4] = {{0.f,0.f,0.f,0.f},{0.f,0.f,0.f,0.f},
                          {0.f,0.f,0.f,0.f},{0.f,0.f,0.f,0.f}};
#pragma unroll
        for (int k0 = 0; k0 < 64; k0 += 32) {
            float4 a0 = *(const float4*)(aptr + k0);
            float4 a1 = *(const float4*)(aptr + k0 + 4);
            __hip_bfloat16 ah[8] = {
                __float2bfloat16(a0.x), __float2bfloat16(a0.y),
                __float2bfloat16(a0.z), __float2bfloat16(a0.w),
                __float2bfloat16(a1.x), __float2bfloat16(a1.y),
                __float2bfloat16(a1.z), __float2bfloat16(a1.w)};
            short8v a = *(const short8v*)ah;
#pragma unroll
            for (int t = 0; t < 4; ++t) {
                short8v bb = *(const short8v*)(&Ws0[half * 64 + t * 16 + m][k0 + g * 8]);
                acc[t] = __builtin_amdgcn_mfma_f32_16x16x32_bf16(a, bb, acc[t], 0, 0, 0);
            }
        }
        int r0 = panel * 16;
        if (half == 0) {
#pragma unroll
            for (int t = 0; t < 4; ++t)
#pragma unroll
                for (int r = 0; r < 4; ++r)
                    Pa[(size_t)(r0 + g * 4 + r) * 64 + t * 16 + m] = acc[t][r];
        } else {
#pragma unroll
            for (int t = 0; t < 4; ++t)
#pragma unroll
                for (int r = 0; r < 4; ++r)
                    Pbb[(size_t)(r0 + g * 4 + r) * 64 + t * 16 + m] =
                        __float2bfloat16(acc[t][r]);
        }
    } else {
        int i = (blk - 625) * 256 + tid;           // < NE exactly
        int d = edst[i];
        int pos = atomicAdd(cursor + d, 1);
        if (pos < CAP) elist[(size_t)d * CAP + pos] = esrc[i];
    }
}

// ---- fused: agg(layer i) for 32 nodes -> LDS + xcatb, then gemm(layer i+1) K=C ----
// 625 blocks; phase A: 4 waves x 8 nodes; phase B: 4 waves = 2 panels x 2 halves.
template <int C>
__global__ __launch_bounds__(256, 4) void fused2_kernel(
    const float* __restrict__ PaIn, const __hip_bfloat16* __restrict__ PbbIn,
    const float* __restrict__ b, const int* __restrict__ cnt,
    const int* __restrict__ elist, __hip_bfloat16* __restrict__ xcatb,
    const __hip_bfloat16* __restrict__ Wt, float* __restrict__ PaOut,
    __hip_bfloat16* __restrict__ PbbOut) {
    __shared__ __hip_bfloat16 newt[32][72];
    int tid = threadIdx.x;
    int w = tid >> 6, lane = tid & 63;
    int base = blockIdx.x * 32;

    // phase A: aggregate 8 nodes per wave
#pragma unroll
    for (int nl = 0; nl < 8; ++nl) {
        int local = w * 8 + nl;
        int node = base + local;
        int c = cnt[node];
        if (c > CAP) c = CAP;
        float mx = bucket_max(elist + (size_t)node * CAP, c, lane, PbbIn);
        float v = fmaxf(PaIn[(size_t)node * 64 + lane] + b[lane] + mx, 0.f);
        __hip_bfloat16 h = __float2bfloat16(v);
        newt[local][lane] = h;
        xcatb[(size_t)node * XSTB + (C - 64) + lane] = h;
    }
    __syncthreads();

    // phase B: all 4 waves; wave w -> panel_local = w>>1, half = w&1
    int pl = w >> 1, half = w & 1;
    int panel = blockIdx.x * 2 + pl;
    int r0 = panel * 16;
    int m = lane & 15, g = lane >> 4;
    const __hip_bfloat16* aptr = xcatb + (size_t)(r0 + m) * XSTB + g * 8;
    const __hip_bfloat16* bptr = Wt + (size_t)(half * 64 + m) * C + g * 8;
    float4v acc[4] = {{0.f,0.f,0.f,0.f},{0.f,0.f,0.f,0.f},
                      {0.f,0.f,0.f,0.f},{0.f,0.f,0.f,0.f}};
#pragma unroll
    for (int k0 = 0; k0 < C; k0 += 32) {
        short8v a;
        if (k0 < C - 64) a = *(const short8v*)(aptr + k0);
        else             a = *(const short8v*)(&newt[pl * 16 + m][k0 - (C - 64) + g * 8]);
#pragma unroll
        for (int t = 0; t < 4; ++t) {
            short8v bb = *(const short8v*)(bptr + (size_t)t * 16 * C + k0);
            acc[t] = __builtin_amdgcn_mfma_f32_16x16x32_bf16(a, bb, acc[t], 0, 0, 0);
        }
    }
    if (half == 0) {
#pragma unroll
        for (int t = 0; t < 4; ++t)
#pragma unroll
            for (int r = 0; r < 4; ++r)
                PaOut[(size_t)(r0 + g * 4 + r) * 64 + t * 16 + m] = acc[t][r];
    } else {
#pragma unroll
        for (int t = 0; t < 4; ++t)
#pragma unroll
            for (int r = 0; r < 4; ++r)
                PbbOut[(size_t)(r0 + g * 4 + r) * 64 + t * 16 + m] =
                    __float2bfloat16(acc[t][r]);
    }
}

// ---- last layer agg + final max (32 nodes/block) ----
__global__ __launch_bounds__(256, 4) void aggf_kernel(
    const float* __restrict__ Pa, const __hip_bfloat16* __restrict__ Pbb,
    const float* __restrict__ b, const int* __restrict__ cnt,
    const int* __restrict__ elist, const __hip_bfloat16* __restrict__ xcatb,
    float* __restrict__ out) {
    __shared__ float sm[4][64];
    int w = threadIdx.x >> 6, lane = threadIdx.x & 63;
    int base = blockIdx.x * 32;
#pragma unroll
    for (int nl = 0; nl < 8; ++nl) {
        int node = base + w * 8 + nl;
        int c = cnt[node];
        if (c > CAP) c = CAP;
        float mx = bucket_max(elist + (size_t)node * CAP, c, lane, Pbb);
        float v = fmaxf(Pa[(size_t)node * 64 + lane] + b[lane] + mx, 0.f);
        sm[w][lane] = v;                      // intra-wave produce/consume
        float m;
        if (lane < 48) {
            bh4 q = *(const bh4*)(xcatb + (size_t)node * XSTB + (lane << 2));
            float f0 = __bfloat162float(q.a), f1 = __bfloat162float(q.b);
            float f2 = __bfloat162float(q.c), f3 = __bfloat162float(q.d);
            m = fmaxf(fmaxf(f0, f1), fmaxf(f2, f3));
        } else {
            const float* p = &sm[w][(lane - 48) << 2];
            m = fmaxf(fmaxf(p[0], p[1]), fmaxf(p[2], p[3]));
        }
        out[(size_t)node * 64 + lane] = m;
    }
}

extern "C" void kernel_launch(void* const* d_in, const int* in_sizes, int n_in,
                              void* d_out, int out_size, void* d_ws, size_t ws_size,
                              hipStream_t stream) {
    const float* x = (const float*)d_in[0];
    const float* W0 = (const float*)d_in[1];
    const float* W1 = (const float*)d_in[3];
    const float* W2 = (const float*)d_in[5];
    const float* b0 = (const float*)d_in[2];
    const float* b1 = (const float*)d_in[4];
    const float* b2 = (const float*)d_in[6];
    const int* eidx = (const int*)d_in[7];
    const int* esrc = eidx;
    const int* edst = eidx + NE;
    float* out = (float*)d_out;

    char* w = (char*)d_ws;
    __hip_bfloat16* xcatb = (__hip_bfloat16*)w;  w += (size_t)NN * XSTB * 2;
    float* PaA = (float*)w;                      w += (size_t)NN * 64 * 4;
    __hip_bfloat16* PbbA = (__hip_bfloat16*)w;   w += (size_t)NN * 64 * 2;
    float* PaB = (float*)w;                      w += (size_t)NN * 64 * 4;
    __hip_bfloat16* PbbB = (__hip_bfloat16*)w;   w += (size_t)NN * 64 * 2;
    __hip_bfloat16* Wt = (__hip_bfloat16*)w;     w += (size_t)WT_TOT * 2;
    int* cursor = (int*)w;                       w += (size_t)NN * 4;
    int* elist = (int*)w;

    k0_kernel<<<1430, 256, 0, stream>>>(x, W1, W2, xcatb, Wt, cursor);
    k1_kernel<<<1875, 256, 0, stream>>>(x, W0, esrc, edst, cursor, elist, PaA, PbbA);
    fused2_kernel<128><<<625, 256, 0, stream>>>(PaA, PbbA, b0, cursor, elist, xcatb,
                                                Wt + WT_OFF1, PaB, PbbB);
    fused2_kernel<192><<<625, 256, 0, stream>>>(PaB, PbbB, b1, cursor, elist, xcatb,
                                                Wt + WT_OFF2, PaA, PbbA);
    aggf_kernel<<<625, 256, 0, stream>>>(PaA, PbbA, b2, cursor, elist, xcatb, out);
}

// Round 10
// 90.522 us; speedup vs baseline: 9.4925x; 1.4041x over previous
//
#include <hip/hip_runtime.h>
#include <hip/hip_bf16.h>

#define NN 20000
#define NE 320000
#define XSTB 256    // xcatb row stride (bf16 elems)
#define CAP 96      // per-node bucket capacity (Poisson(16): P(>=96)~1e-47)

typedef __attribute__((ext_vector_type(8))) short short8v;
typedef __attribute__((ext_vector_type(4))) float float4v;

struct bh4 { __hip_bfloat16 a, b, c, d; };

// Global Wt layout (layers 1,2; layer 0 built in-LDS by gemm0 blocks):
// per layer [128][K] bf16: rows 0..63 = (Wtop-Wbot)^T -> Pa; rows 64..127 = Wbot^T -> Pb
#define WT_OFF1 0
#define WT_OFF2 (128 * 128)
#define WT_TOT  (128 * 128 + 128 * 192)   // 40960 elems

__device__ __forceinline__ float bucket_max(const int* __restrict__ el, int c, int lane,
                                            const __hip_bfloat16* __restrict__ Pbb) {
    float mx = -INFINITY;
    int i = 0;
    for (; i + 4 <= c; i += 4) {
        int s0 = el[i], s1 = el[i + 1], s2 = el[i + 2], s3 = el[i + 3];
        float v0 = __bfloat162float(Pbb[(size_t)s0 * 64 + lane]);
        float v1 = __bfloat162float(Pbb[(size_t)s1 * 64 + lane]);
        float v2 = __bfloat162float(Pbb[(size_t)s2 * 64 + lane]);
        float v3 = __bfloat162float(Pbb[(size_t)s3 * 64 + lane]);
        mx = fmaxf(mx, fmaxf(fmaxf(v0, v1), fmaxf(v2, v3)));
    }
    for (; i < c; ++i)
        mx = fmaxf(mx, __bfloat162float(Pbb[(size_t)el[i] * 64 + lane]));
    return mx;
}

// ---- KZ: zero cursor (tiny) ----
__global__ __launch_bounds__(256) void kz_kernel(int* __restrict__ cursor) {
    int q = blockIdx.x * 256 + threadIdx.x;        // 5120 >= 5000 int4
    if (q < NN / 4) *((int4*)cursor + q) = make_int4(0, 0, 0, 0);
}

// ---- K1: gemm0 || bucket CSR fill || x->bf16 || Wt(1,2) build ----
// blocks [0,625): gemm0; [625,1875): fill; [1875,3125): xconv; [3125,3285): Wt.
__global__ __launch_bounds__(256, 4) void k1_kernel(
    const float* __restrict__ x, const float* __restrict__ W0,
    const float* __restrict__ W1, const float* __restrict__ W2,
    const int* __restrict__ esrc, const int* __restrict__ edst,
    __hip_bfloat16* __restrict__ xcatb, __hip_bfloat16* __restrict__ Wt,
    int* __restrict__ cursor, int* __restrict__ elist,
    float* __restrict__ Pa, __hip_bfloat16* __restrict__ Pbb) {
    __shared__ __hip_bfloat16 Ws0[128][72];
    int blk = blockIdx.x, tid = threadIdx.x;
    int w = tid >> 6, lane = tid & 63;

    if (blk < 625) {
        // build transformed W0 into LDS (coalesced over W0 rows)
        for (int e = tid; e < 4096; e += 256) {
            int r = e >> 6, j = e & 63;            // r = k index, j = out col
            float wt = W0[r * 64 + j];
            float wb = W0[(64 + r) * 64 + j];
            Ws0[j][r] = __float2bfloat16(wt - wb);
            Ws0[64 + j][r] = __float2bfloat16(wb);
        }
        __syncthreads();
        int wid = blk * 4 + w;                     // 0..2499
        int panel = wid >> 1, half = wid & 1;
        int m = lane & 15, g = lane >> 4;
        const float* aptr = x + (size_t)(panel * 16 + m) * 64 + g * 8;
        float4v acc[4] = {{0.f,0.f,0.f,0.f},{0.f,0.f,0.f,0.f},
                          {0.f,0.f,0.f,0.f},{0.f,0.f,0.f,0.f}};
#pragma unroll
        for (int k0 = 0; k0 < 64; k0 += 32) {
            float4 a0 = *(const float4*)(aptr + k0);
            float4 a1 = *(const float4*)(aptr + k0 + 4);
            __hip_bfloat16 ah[8] = {
                __float2bfloat16(a0.x), __float2bfloat16(a0.y),
                __float2bfloat16(a0.z), __float2bfloat16(a0.w),
                __float2bfloat16(a1.x), __float2bfloat16(a1.y),
                __float2bfloat16(a1.z), __float2bfloat16(a1.w)};
            short8v a = *(const short8v*)ah;
#pragma unroll
            for (int t = 0; t < 4; ++t) {
                short8v bb = *(const short8v*)(&Ws0[half * 64 + t * 16 + m][k0 + g * 8]);
                acc[t] = __builtin_amdgcn_mfma_f32_16x16x32_bf16(a, bb, acc[t], 0, 0, 0);
            }
        }
        int r0 = panel * 16;
        if (half == 0) {
#pragma unroll
            for (int t = 0; t < 4; ++t)
#pragma unroll
                for (int r = 0; r < 4; ++r)
                    Pa[(size_t)(r0 + g * 4 + r) * 64 + t * 16 + m] = acc[t][r];
        } else {
#pragma unroll
            for (int t = 0; t < 4; ++t)
#pragma unroll
                for (int r = 0; r < 4; ++r)
                    Pbb[(size_t)(r0 + g * 4 + r) * 64 + t * 16 + m] =
                        __float2bfloat16(acc[t][r]);
        }
    } else if (blk < 1875) {
        int i = (blk - 625) * 256 + tid;           // < NE exactly
        int d = edst[i];
        int pos = atomicAdd(cursor + d, 1);
        if (pos < CAP) elist[(size_t)d * CAP + pos] = esrc[i];
    } else if (blk < 3125) {
        int i = (blk - 1875) * 256 + tid;          // 320000 quads exactly
        int n = i >> 4, c4 = (i & 15) << 2;
        float4 v = *(const float4*)(x + (size_t)n * 64 + c4);
        bh4 o = {__float2bfloat16(v.x), __float2bfloat16(v.y),
                 __float2bfloat16(v.z), __float2bfloat16(v.w)};
        *(bh4*)(xcatb + (size_t)n * XSTB + c4) = o;
    } else {
        int e = (blk - 3125) * 256 + tid;          // 40960 exactly
        const float* W;
        int K, off;
        if (e < WT_OFF2) { W = W1; K = 128; off = WT_OFF1; }
        else             { W = W2; K = 192; off = WT_OFF2; }
        int el = e - off;
        int j = el / K, k = el - j * K;
        float wv;
        if (j < 64) wv = W[(size_t)k * 64 + j] - W[(size_t)(K + k) * 64 + j];
        else        wv = W[(size_t)(K + k) * 64 + (j - 64)];
        Wt[(size_t)off + (size_t)j * K + k] = __float2bfloat16(wv);
    }
}

// ---- fused: agg(layer i) for 16 nodes -> LDS + xcatb, then gemm(layer i+1) K=C ----
// 1250 blocks. Phase A: 4 waves x 4 nodes (max gather TLP). Phase B: waves 0,1.
template <int C>
__global__ __launch_bounds__(256, 4) void fused_kernel(
    const float* __restrict__ PaIn, const __hip_bfloat16* __restrict__ PbbIn,
    const float* __restrict__ b, const int* __restrict__ cnt,
    const int* __restrict__ elist, __hip_bfloat16* __restrict__ xcatb,
    const __hip_bfloat16* __restrict__ Wt, float* __restrict__ PaOut,
    __hip_bfloat16* __restrict__ PbbOut) {
    __shared__ __hip_bfloat16 newt[16][72];
    int tid = threadIdx.x;
    int w = tid >> 6, lane = tid & 63;
    int panel = blockIdx.x;
    int r0 = panel * 16;

    // phase A: aggregate 4 nodes per wave
#pragma unroll
    for (int nl = 0; nl < 4; ++nl) {
        int local = w * 4 + nl;
        int node = r0 + local;
        int c = cnt[node];
        if (c > CAP) c = CAP;
        float mx = bucket_max(elist + (size_t)node * CAP, c, lane, PbbIn);
        float v = fmaxf(PaIn[(size_t)node * 64 + lane] + b[lane] + mx, 0.f);
        __hip_bfloat16 h = __float2bfloat16(v);
        newt[local][lane] = h;
        xcatb[(size_t)node * XSTB + (C - 64) + lane] = h;
    }
    __syncthreads();
    if (w >= 2) return;

    // phase B: MFMA gemm for this panel, half = w
    int half = w;
    int m = lane & 15, g = lane >> 4;
    const __hip_bfloat16* aptr = xcatb + (size_t)(r0 + m) * XSTB + g * 8;
    const __hip_bfloat16* bptr = Wt + (size_t)(half * 64 + m) * C + g * 8;
    float4v acc[4] = {{0.f,0.f,0.f,0.f},{0.f,0.f,0.f,0.f},
                      {0.f,0.f,0.f,0.f},{0.f,0.f,0.f,0.f}};
#pragma unroll
    for (int k0 = 0; k0 < C; k0 += 32) {
        short8v a;
        if (k0 < C - 64) a = *(const short8v*)(aptr + k0);
        else             a = *(const short8v*)(&newt[m][k0 - (C - 64) + g * 8]);
#pragma unroll
        for (int t = 0; t < 4; ++t) {
            short8v bb = *(const short8v*)(bptr + (size_t)t * 16 * C + k0);
            acc[t] = __builtin_amdgcn_mfma_f32_16x16x32_bf16(a, bb, acc[t], 0, 0, 0);
        }
    }
    if (half == 0) {
#pragma unroll
        for (int t = 0; t < 4; ++t)
#pragma unroll
            for (int r = 0; r < 4; ++r)
                PaOut[(size_t)(r0 + g * 4 + r) * 64 + t * 16 + m] = acc[t][r];
    } else {
#pragma unroll
        for (int t = 0; t < 4; ++t)
#pragma unroll
            for (int r = 0; r < 4; ++r)
                PbbOut[(size_t)(r0 + g * 4 + r) * 64 + t * 16 + m] =
                    __float2bfloat16(acc[t][r]);
    }
}

// ---- last layer agg + final max (4 nodes/block, 1 per wave) ----
__global__ __launch_bounds__(256, 4) void aggf_kernel(
    const float* __restrict__ Pa, const __hip_bfloat16* __restrict__ Pbb,
    const float* __restrict__ b, const int* __restrict__ cnt,
    const int* __restrict__ elist, const __hip_bfloat16* __restrict__ xcatb,
    float* __restrict__ out) {
    __shared__ float sm[4][64];
    int w = threadIdx.x >> 6, lane = threadIdx.x & 63;
    int node = blockIdx.x * 4 + w;                 // 5000*4 = 20000 exactly
    int c = cnt[node];
    if (c > CAP) c = CAP;
    float mx = bucket_max(elist + (size_t)node * CAP, c, lane, Pbb);
    float v = fmaxf(Pa[(size_t)node * 64 + lane] + b[lane] + mx, 0.f);
    sm[w][lane] = v;                               // intra-wave produce/consume
    float m;
    if (lane < 48) {
        bh4 q = *(const bh4*)(xcatb + (size_t)node * XSTB + (lane << 2));
        float f0 = __bfloat162float(q.a), f1 = __bfloat162float(q.b);
        float f2 = __bfloat162float(q.c), f3 = __bfloat162float(q.d);
        m = fmaxf(fmaxf(f0, f1), fmaxf(f2, f3));
    } else {
        const float* p = &sm[w][(lane - 48) << 2];
        m = fmaxf(fmaxf(p[0], p[1]), fmaxf(p[2], p[3]));
    }
    out[(size_t)node * 64 + lane] = m;
}

extern "C" void kernel_launch(void* const* d_in, const int* in_sizes, int n_in,
                              void* d_out, int out_size, void* d_ws, size_t ws_size,
                              hipStream_t stream) {
    const float* x = (const float*)d_in[0];
    const float* W0 = (const float*)d_in[1];
    const float* W1 = (const float*)d_in[3];
    const float* W2 = (const float*)d_in[5];
    const float* b0 = (const float*)d_in[2];
    const float* b1 = (const float*)d_in[4];
    const float* b2 = (const float*)d_in[6];
    const int* eidx = (const int*)d_in[7];
    const int* esrc = eidx;
    const int* edst = eidx + NE;
    float* out = (float*)d_out;

    char* w = (char*)d_ws;
    __hip_bfloat16* xcatb = (__hip_bfloat16*)w;  w += (size_t)NN * XSTB * 2;
    float* PaA = (float*)w;                      w += (size_t)NN * 64 * 4;
    __hip_bfloat16* PbbA = (__hip_bfloat16*)w;   w += (size_t)NN * 64 * 2;
    float* PaB = (float*)w;                      w += (size_t)NN * 64 * 4;
    __hip_bfloat16* PbbB = (__hip_bfloat16*)w;   w += (size_t)NN * 64 * 2;
    __hip_bfloat16* Wt = (__hip_bfloat16*)w;     w += (size_t)WT_TOT * 2;
    int* cursor = (int*)w;                       w += (size_t)NN * 4;
    int* elist = (int*)w;

    kz_kernel<<<20, 256, 0, stream>>>(cursor);
    k1_kernel<<<3285, 256, 0, stream>>>(x, W0, W1, W2, esrc, edst, xcatb, Wt,
                                        cursor, elist, PaA, PbbA);
    fused_kernel<128><<<1250, 256, 0, stream>>>(PaA, PbbA, b0, cursor, elist, xcatb,
                                                Wt + WT_OFF1, PaB, PbbB);
    fused_kernel<192><<<1250, 256, 0, stream>>>(PaB, PbbB, b1, cursor, elist, xcatb,
                                                Wt + WT_OFF2, PaA, PbbA);
    aggf_kernel<<<5000, 256, 0, stream>>>(PaA, PbbA, b2, cursor, elist, xcatb, out);
}